// Round 20
// baseline (397.184 us; speedup 1.0000x reference)
//
#include <hip/hip_runtime.h>
#include <hip/hip_fp16.h>

#define CIN   64
#define COUT  128
#define HIN   128
#define WIN   128
#define HOUT  126
#define WOUT  126
#define HP    63
#define WP    63
#define NB    32
#define NG    16
#define EPS   1e-5f
#define KTOT  576            // 9 * 64, k = (kh*3+kw)*64 + ci
#define NTILE 252            // rp*4 + ct

// xt layout (LINEAR): [b][row][col][64 ci] f16
#define XTROW (WIN * 64)          // 8192 ushorts per row
#define XTIMG (HIN * XTROW)       // 1,048,576 ushorts per image

typedef __attribute__((ext_vector_type(8))) _Float16 half8;
typedef __attribute__((ext_vector_type(4))) float f32x4;

// ---- weight prep: cw[co][ci][3][3] f32 -> wt[co][k] f16, k=(kh*3+kw)*64+ci
__global__ __launch_bounds__(256) void wprep_kernel(
    const float* __restrict__ cw, ushort* __restrict__ wt)
{
    int idx = blockIdx.x * 256 + threadIdx.x;
    if (idx >= COUT * KTOT) return;
    int co = idx / KTOT, k = idx - co * KTOT;
    int khw = k >> 6, ci = k & 63;
    float v = cw[(co * CIN + ci) * 9 + khw];
    wt[idx] = __half_as_ushort(__float2half(v));
}

// ---- x prep: x[b][ci][row][col] f32 -> xt[b][row][col][ci] f16 (linear)
__global__ __launch_bounds__(512) void xprep_kernel(
    const float* __restrict__ x, ushort* __restrict__ xt)
{
    const int tid = threadIdx.x;
    const int row = blockIdx.x & 127, b = blockIdx.x >> 7;
    const int cig = tid >> 6;                 // 0..7
    const float* xb = x + (size_t)b * (CIN * HIN * WIN) + (size_t)row * WIN;
    ushort* ob = xt + (size_t)b * XTIMG + (size_t)row * XTROW;
#pragma unroll
    for (int ch = 0; ch < 2; ++ch) {
        int col = ch * 64 + (tid & 63);
        ushort v[8];
#pragma unroll
        for (int j = 0; j < 8; ++j)
            v[j] = __half_as_ushort(__float2half(
                xb[(size_t)(cig * 8 + j) * (HIN * WIN) + col]));
        uint4 pk;
        pk.x = (unsigned)v[0] | ((unsigned)v[1] << 16);
        pk.y = (unsigned)v[2] | ((unsigned)v[3] << 16);
        pk.z = (unsigned)v[4] | ((unsigned)v[5] << 16);
        pk.w = (unsigned)v[6] | ((unsigned)v[7] << 16);
        *(uint4*)(ob + col * 64 + cig * 8) = pk;
    }
}

// ---- conv implicit GEMM + fused signed maxpool: NO LDS, NO BARRIERS.
// block = 2 rows x 32 cols x 128 couts, 4 independent waves; A and B fragments
// streamed directly from L1/L2 (xt tile + weights are cache-resident).
__global__ __launch_bounds__(256, 4) void conv_mfma_kernel(
    const ushort* __restrict__ xt, const ushort* __restrict__ wt,
    const float* __restrict__ cb, const float* __restrict__ gwv,
    const float* __restrict__ scv, float* __restrict__ m,
    float* __restrict__ partials)
{
    const int tid = threadIdx.x;
    // XCD swizzle: 8064 blocks = 8 XCDs x 1008; each XCD gets 4 whole images
    const int bid = blockIdx.x;
    const int w   = (bid & 7) * 1008 + (bid >> 3);
    const int b   = w / 252;
    const int r   = w - b * 252;
    const int rp  = r >> 2;            // 0..62 row pair == pool row
    const int ct  = r & 3;             // 32-col tile
    const int r0x = rp * 2;            // first x row needed (<=124)

    const int l = tid & 63, wg = tid >> 6;    // wg: cout group of 32
    const int l15 = l & 15, lhi = l >> 4;

    f32x4 acc[2][4];                   // [mt][nt]; nt = row*2 + col16
#pragma unroll
    for (int mt = 0; mt < 2; ++mt)
#pragma unroll
        for (int nt = 0; nt < 4; ++nt)
            acc[mt][nt] = (f32x4){0.f, 0.f, 0.f, 0.f};

    // per-lane fragment bases (all K-loop offsets are compile-time constants)
    const ushort* xlane = xt + (size_t)b * XTIMG + (size_t)r0x * XTROW
                        + (size_t)(ct * 32 + l15) * 64 + lhi * 8;
    const ushort* wb = wt + (size_t)(wg * 32 + l15) * KTOT + lhi * 8;

#pragma unroll
    for (int khw = 0; khw < 9; ++khw) {
        const int kh = khw / 3, kw = khw - kh * 3;
#pragma unroll
        for (int cip = 0; cip < 2; ++cip) {
            half8 a0 = *(const half8*)(wb + khw * 64 + cip * 32);
            half8 a1 = *(const half8*)(wb + 16 * KTOT + khw * 64 + cip * 32);
            half8 bv[4];
#pragma unroll
            for (int nt = 0; nt < 4; ++nt)
                bv[nt] = *(const half8*)(xlane
                        + (size_t)((nt >> 1) + kh) * XTROW
                        + ((nt & 1) * 16 + kw) * 64 + cip * 32);
#pragma unroll
            for (int nt = 0; nt < 4; ++nt) {
                acc[0][nt] = __builtin_amdgcn_mfma_f32_16x16x32_f16(
                    a0, bv[nt], acc[0][nt], 0, 0, 0);
                acc[1][nt] = __builtin_amdgcn_mfma_f32_16x16x32_f16(
                    a1, bv[nt], acc[1][nt], 0, 0, 0);
            }
        }
    }

    // ---- epilogue: bias, signed 2x2 pool -> m, group partials
#pragma unroll
    for (int mt = 0; mt < 2; ++mt) {
        float s1 = 0.f, s2 = 0.f;
#pragma unroll
        for (int r2 = 0; r2 < 4; ++r2) {
            int co = wg * 32 + mt * 16 + lhi * 4 + r2;
            float bias = cb[co];
            bool usemax = (gwv[co] * scv[co]) >= 0.f;
#pragma unroll
            for (int nc = 0; nc < 2; ++nc) {
                float v0 = acc[mt][nc][r2] + bias;       // row 0 of pair
                float v1 = acc[mt][2 + nc][r2] + bias;   // row 1 of pair
                int col = ct * 32 + nc * 16 + l15;
                if (col < WOUT) { s1 += v0 + v1; s2 += v0 * v0 + v1 * v1; }
                float a = usemax ? fmaxf(v0, v1) : fminf(v0, v1);
                float xo = __shfl_xor(a, 1);
                float wv = usemax ? fmaxf(a, xo) : fminf(a, xo);
                int wp = col >> 1;
                if (((l15 & 1) == 0) && wp < WP)
                    m[(((size_t)(b * COUT + co)) * HP + rp) * WP + wp] = wv;
            }
        }
        // reduce over 16 l15 lanes, then combine lhi pairs
#pragma unroll
        for (int d = 1; d < 16; d <<= 1) {
            s1 += __shfl_xor(s1, d);
            s2 += __shfl_xor(s2, d);
        }
        s1 += __shfl_xor(s1, 16);
        s2 += __shfl_xor(s2, 16);
        if (l15 == 0 && (lhi & 1) == 0) {
            int g = wg * 4 + mt * 2 + (lhi >> 1);     // couts [8g, 8g+8)
            size_t pidx = (((size_t)b * NG + g) * NTILE + (rp * 4 + ct)) * 2;
            partials[pidx + 0] = s1;
            partials[pidx + 1] = s2;
        }
    }
}

// ---- stats: one wave per (b,g); parallel loads + shfl reduce
__global__ __launch_bounds__(64) void stats_kernel(
    const float* __restrict__ partials, float* __restrict__ stats)
{
    int t = blockIdx.x;                // 0..511 = (b,g)
    int lane = threadIdx.x;            // 0..63
    float s1 = 0.f, s2 = 0.f;
    for (int j = lane; j < NTILE; j += 64) {
        s1 += partials[((size_t)t * NTILE + j) * 2 + 0];
        s2 += partials[((size_t)t * NTILE + j) * 2 + 1];
    }
#pragma unroll
    for (int d = 1; d < 64; d <<= 1) {
        s1 += __shfl_xor(s1, d);
        s2 += __shfl_xor(s2, d);
    }
    if (lane == 0) {
        const float N = 8.f * HOUT * WOUT;
        float mean = s1 / N;
        float var = s2 / N - mean * mean;
        stats[t * 2 + 0] = mean;
        stats[t * 2 + 1] = rsqrtf(var + EPS);
    }
}

// ---- final: out = clamp(ga*m + gbb); pool already applied (sign-aware)
__global__ __launch_bounds__(256) void final_kernel(
    const float* __restrict__ m, const float* __restrict__ stats,
    const float* __restrict__ gw, const float* __restrict__ gb,
    const float* __restrict__ sc, float* __restrict__ out)
{
    int idx = blockIdx.x * 256 + threadIdx.x;
    if (idx >= NB * COUT * HP * WP) return;
    int t = idx / WP;
    t /= HP;
    int c = t % COUT;
    int b = t / COUT;
    int g = c >> 3;

    float mean = stats[(b * NG + g) * 2 + 0];
    float rstd = stats[(b * NG + g) * 2 + 1];
    float ga = rstd * gw[c] * sc[c];
    float gbb = (gb[c] - mean * rstd * gw[c]) * sc[c];

    float v = fmaf(m[idx], ga, gbb);
    out[idx] = fminf(fmaxf(v, 0.f), 1.f);
}

extern "C" void kernel_launch(void* const* d_in, const int* in_sizes, int n_in,
                              void* d_out, int out_size, void* d_ws, size_t ws_size,
                              hipStream_t stream)
{
    const float* x  = (const float*)d_in[0];
    const float* cw = (const float*)d_in[1];
    const float* cbias = (const float*)d_in[2];
    const float* gw = (const float*)d_in[3];
    const float* gb = (const float*)d_in[4];
    const float* sc = (const float*)d_in[5];
    float* out = (float*)d_out;

    // ws: m 65.0 MB + partials 1.0 MB + stats 4 KB + wt 147 KB + xt 67.1 MB
    //   ~= 133.5 MB (trailing ws slack absorbs the 256-B halo over-read)
    const size_t MSZ = (size_t)NB * COUT * HP * WP;              // 16,257,024 f32
    float* m        = (float*)d_ws;
    float* partials = m + MSZ;                                   // 32*16*252*2 f32
    float* stats    = partials + (size_t)NB * NG * NTILE * 2;    // 1024 f32
    ushort* wt      = (ushort*)(stats + 1024);                   // 128*576 f16
    ushort* xtb     = wt + (size_t)COUT * KTOT;                  // 32 x 2 MB f16

    hipLaunchKernelGGL(wprep_kernel, dim3((COUT * KTOT + 255) / 256), dim3(256),
                       0, stream, cw, wt);

    hipLaunchKernelGGL(xprep_kernel, dim3(NB * HIN), dim3(512), 0, stream,
                       x, xtb);

    hipLaunchKernelGGL(conv_mfma_kernel, dim3(8064), dim3(256), 0, stream,
                       xtb, wt, cbias, gw, sc, m, partials);

    hipLaunchKernelGGL(stats_kernel, dim3(NB * NG), dim3(64), 0, stream,
                       partials, stats);

    int total = NB * COUT * HP * WP;
    hipLaunchKernelGGL(final_kernel, dim3((total + 255) / 256), dim3(256), 0, stream,
                       m, stats, gw, gb, sc, out);
}

// Round 21
// 231.193 us; speedup vs baseline: 1.7180x; 1.7180x over previous
//
#include <hip/hip_runtime.h>
#include <hip/hip_fp16.h>

#define CIN   64
#define COUT  128
#define HIN   128
#define WIN   128
#define HOUT  126
#define WOUT  126
#define HP    63
#define WP    63
#define NB    32
#define NG    16
#define EPS   1e-5f
#define KTOT  576            // 9 * 64, k = (kh*3+kw)*64 + ci
#define NTILE 252            // rp*4 + ct

// xt layout: [b][row][col][slot(8)][8 ci] f16, slot = cig ^ (col & 7)
#define XTROW (WIN * 64)          // 8192 ushorts per row
#define XTIMG (HIN * XTROW)       // 1,048,576 ushorts per image

// conv LDS tile: [4 rows][34 cols][64 ci] f16 = 17408 B (pre-swizzled copy of xt)
#define LROW  2176                // ushorts per row (34 * 64)
#define LROWB 4352                // bytes per row

typedef __attribute__((ext_vector_type(8))) _Float16 half8;
typedef __attribute__((ext_vector_type(4))) float f32x4;

#define GLOAD_LDS(gsrc, ldst)                                              \
    __builtin_amdgcn_global_load_lds(                                      \
        (const __attribute__((address_space(1))) void*)(gsrc),             \
        (__attribute__((address_space(3))) void*)(ldst), 16, 0, 0)

// ---- weight prep: cw[co][ci][3][3] f32 -> wt[co][k] f16, k=(kh*3+kw)*64+ci
__global__ __launch_bounds__(256) void wprep_kernel(
    const float* __restrict__ cw, ushort* __restrict__ wt)
{
    int idx = blockIdx.x * 256 + threadIdx.x;
    if (idx >= COUT * KTOT) return;
    int co = idx / KTOT, k = idx - co * KTOT;
    int khw = k >> 6, ci = k & 63;
    float v = cw[(co * CIN + ci) * 9 + khw];
    wt[idx] = __half_as_ushort(__float2half(v));
}

// ---- x prep: x[b][ci][row][col] f32 -> xt[b][row][col][slot][8ci] f16 (swizzled)
__global__ __launch_bounds__(512) void xprep_kernel(
    const float* __restrict__ x, ushort* __restrict__ xt)
{
    const int tid = threadIdx.x;
    const int row = blockIdx.x & 127, b = blockIdx.x >> 7;
    const int cig = tid >> 6;                 // 0..7
    const float* xb = x + (size_t)b * (CIN * HIN * WIN) + (size_t)row * WIN;
    ushort* ob = xt + (size_t)b * XTIMG + (size_t)row * XTROW;
#pragma unroll
    for (int ch = 0; ch < 2; ++ch) {
        int col = ch * 64 + (tid & 63);
        ushort v[8];
#pragma unroll
        for (int j = 0; j < 8; ++j)
            v[j] = __half_as_ushort(__float2half(
                xb[(size_t)(cig * 8 + j) * (HIN * WIN) + col]));
        uint4 pk;
        pk.x = (unsigned)v[0] | ((unsigned)v[1] << 16);
        pk.y = (unsigned)v[2] | ((unsigned)v[3] << 16);
        pk.z = (unsigned)v[4] | ((unsigned)v[5] << 16);
        pk.w = (unsigned)v[6] | ((unsigned)v[7] << 16);
        *(uint4*)(ob + col * 64 + ((cig ^ (col & 7)) * 8)) = pk;
    }
}

// ---- conv implicit GEMM + fused signed maxpool: block = 2 rows x 32 cols x
// 128 couts, 4 waves. x staged from xt via global_load_lds (no convert VALU);
// B-frag reads use the pre-applied XOR swizzle. Writes pooled m + partials.
// (r15 structure verbatim — proven 175 us, VGPR 60, zero bank conflicts.)
__global__ __launch_bounds__(256, 4) void conv_mfma_kernel(
    const ushort* __restrict__ xt, const ushort* __restrict__ wt,
    const float* __restrict__ cb, const float* __restrict__ gwv,
    const float* __restrict__ scv, float* __restrict__ m,
    float* __restrict__ partials)
{
    __shared__ ushort xs[4 * LROW];           // 17408 B

    const int tid = threadIdx.x;
    // XCD swizzle: 8064 blocks = 8 XCDs x 1008; each XCD gets 4 whole images
    const int bid = blockIdx.x;
    const int w   = (bid & 7) * 1008 + (bid >> 3);
    const int b   = w / 252;
    const int r   = w - b * 252;
    const int rp  = r >> 2;            // 0..62 row pair == pool row
    const int ct  = r & 3;             // 32-col tile
    const int r0x = rp * 2;            // first x row needed (<=124)

    const int l = tid & 63, wg = tid >> 6;    // wg: cout group of 32
    const int l15 = l & 15, lhi = l >> 4;

    // ---- stage 4 rows x 34 cols x 64 ci: 1088 x 16B contiguous-span copies
    const ushort* xtb = xt + (size_t)b * XTIMG + (size_t)r0x * XTROW
                      + (size_t)(ct * 32) * 64;
#pragma unroll
    for (int t = 0; t < 5; ++t) {
        int idx = t * 256 + tid;
        if (idx < 1088) {                     // wave-uniform split (1088 = 17*64)
            int row = idx / 272;              // 272 tasks of 16B per row
            int within = idx - row * 272;
            GLOAD_LDS(xtb + (size_t)row * XTROW + within * 8, &xs[idx * 8]);
        }
    }
    __syncthreads();

    f32x4 acc[2][4];                   // [mt][nt]; nt = row*2 + col16
#pragma unroll
    for (int mt = 0; mt < 2; ++mt)
#pragma unroll
        for (int nt = 0; nt < 4; ++nt)
            acc[mt][nt] = (f32x4){0.f, 0.f, 0.f, 0.f};

    // A-fragment base (cout tiles wg*32 + mt*16)
    const ushort* wb = wt + (size_t)(wg * 32 + l15) * KTOT + lhi * 8;
    const char* xsb = (const char*)xs;

#pragma unroll
    for (int khw = 0; khw < 9; ++khw) {
        const int kh = khw / 3, kw = khw - kh * 3;
        const int c7 = (l15 + kw) & 7;
#pragma unroll
        for (int cip = 0; cip < 2; ++cip) {
            half8 a0 = *(const half8*)(wb + khw * 64 + cip * 32);
            half8 a1 = *(const half8*)(wb + 16 * KTOT + khw * 64 + cip * 32);
            const int s = ((cip * 4 + lhi) ^ c7) * 16;
            half8 bv[4];
#pragma unroll
            for (int nt = 0; nt < 4; ++nt)
                bv[nt] = *(const half8*)(xsb + ((nt >> 1) + kh) * LROWB
                        + ((nt & 1) * 16 + kw + l15) * 128 + s);
#pragma unroll
            for (int nt = 0; nt < 4; ++nt) {
                acc[0][nt] = __builtin_amdgcn_mfma_f32_16x16x32_f16(
                    a0, bv[nt], acc[0][nt], 0, 0, 0);
                acc[1][nt] = __builtin_amdgcn_mfma_f32_16x16x32_f16(
                    a1, bv[nt], acc[1][nt], 0, 0, 0);
            }
        }
    }

    // ---- epilogue: bias, signed 2x2 pool -> m, group partials
#pragma unroll
    for (int mt = 0; mt < 2; ++mt) {
        float s1 = 0.f, s2 = 0.f;
#pragma unroll
        for (int r2 = 0; r2 < 4; ++r2) {
            int co = wg * 32 + mt * 16 + lhi * 4 + r2;
            float bias = cb[co];
            bool usemax = (gwv[co] * scv[co]) >= 0.f;
#pragma unroll
            for (int nc = 0; nc < 2; ++nc) {
                float v0 = acc[mt][nc][r2] + bias;       // row 0 of pair
                float v1 = acc[mt][2 + nc][r2] + bias;   // row 1 of pair
                int col = ct * 32 + nc * 16 + l15;
                if (col < WOUT) { s1 += v0 + v1; s2 += v0 * v0 + v1 * v1; }
                float a = usemax ? fmaxf(v0, v1) : fminf(v0, v1);
                float xo = __shfl_xor(a, 1);
                float wv = usemax ? fmaxf(a, xo) : fminf(a, xo);
                int wp = col >> 1;
                if (((l15 & 1) == 0) && wp < WP)
                    m[(((size_t)(b * COUT + co)) * HP + rp) * WP + wp] = wv;
            }
        }
        // reduce over 16 l15 lanes, then combine lhi pairs
#pragma unroll
        for (int d = 1; d < 16; d <<= 1) {
            s1 += __shfl_xor(s1, d);
            s2 += __shfl_xor(s2, d);
        }
        s1 += __shfl_xor(s1, 16);
        s2 += __shfl_xor(s2, 16);
        if (l15 == 0 && (lhi & 1) == 0) {
            int g = wg * 4 + mt * 2 + (lhi >> 1);     // couts [8g, 8g+8)
            size_t pidx = (((size_t)b * NG + g) * NTILE + (rp * 4 + ct)) * 2;
            partials[pidx + 0] = s1;
            partials[pidx + 1] = s2;
        }
    }
}

// ---- stats: one wave per (b,g); parallel loads + shfl reduce (deterministic)
__global__ __launch_bounds__(64) void stats_kernel(
    const float* __restrict__ partials, float* __restrict__ stats)
{
    int t = blockIdx.x;                // 0..511 = (b,g)
    int lane = threadIdx.x;            // 0..63
    float s1 = 0.f, s2 = 0.f;
    for (int j = lane; j < NTILE; j += 64) {
        s1 += partials[((size_t)t * NTILE + j) * 2 + 0];
        s2 += partials[((size_t)t * NTILE + j) * 2 + 1];
    }
#pragma unroll
    for (int d = 1; d < 64; d <<= 1) {
        s1 += __shfl_xor(s1, d);
        s2 += __shfl_xor(s2, d);
    }
    if (lane == 0) {
        const float N = 8.f * HOUT * WOUT;
        float mean = s1 / N;
        float var = s2 / N - mean * mean;
        stats[t * 2 + 0] = mean;
        stats[t * 2 + 1] = rsqrtf(var + EPS);
    }
}

// ---- final: out = clamp(ga*m + gbb), float4 (16,257,024 = 4 * 4,064,256)
__global__ __launch_bounds__(256) void final_kernel(
    const f32x4* __restrict__ m4, const float* __restrict__ stats,
    const float* __restrict__ gw, const float* __restrict__ gb,
    const float* __restrict__ sc, f32x4* __restrict__ out4)
{
    int idx = blockIdx.x * 256 + threadIdx.x;
    if (idx >= (NB * COUT * HP * WP) / 4) return;
    f32x4 v = m4[idx];
    f32x4 o;
    const int e0 = idx * 4;
#pragma unroll
    for (int j = 0; j < 4; ++j) {
        int e = e0 + j;
        int plane = e / (HP * WP);        // b*COUT + c  (const divide -> magic mul)
        int c = plane & 127;
        int b = plane >> 7;
        int g = c >> 3;
        float mean = stats[(b * NG + g) * 2 + 0];
        float rstd = stats[(b * NG + g) * 2 + 1];
        float ga = rstd * gw[c] * sc[c];
        float gbb = (gb[c] - mean * rstd * gw[c]) * sc[c];
        o[j] = fminf(fmaxf(fmaf(v[j], ga, gbb), 0.f), 1.f);
    }
    out4[idx] = o;
}

extern "C" void kernel_launch(void* const* d_in, const int* in_sizes, int n_in,
                              void* d_out, int out_size, void* d_ws, size_t ws_size,
                              hipStream_t stream)
{
    const float* x  = (const float*)d_in[0];
    const float* cw = (const float*)d_in[1];
    const float* cbias = (const float*)d_in[2];
    const float* gw = (const float*)d_in[3];
    const float* gb = (const float*)d_in[4];
    const float* sc = (const float*)d_in[5];

    // ws: m 65.0 MB + partials 1.0 MB + stats 4 KB + wt 147 KB + xt 67.1 MB
    //   ~= 133.5 MB  (well under 256 MiB)
    const size_t MSZ = (size_t)NB * COUT * HP * WP;              // 16,257,024 f32
    float* m        = (float*)d_ws;
    float* partials = m + MSZ;                                   // 32*16*252*2 f32
    float* stats    = partials + (size_t)NB * NG * NTILE * 2;    // 1024 f32
    ushort* wt      = (ushort*)(stats + 1024);                   // 128*576 f16
    ushort* xtb     = wt + (size_t)COUT * KTOT;                  // 32 x 2 MB f16

    hipLaunchKernelGGL(wprep_kernel, dim3((COUT * KTOT + 255) / 256), dim3(256),
                       0, stream, cw, wt);

    hipLaunchKernelGGL(xprep_kernel, dim3(NB * HIN), dim3(512), 0, stream,
                       x, xtb);

    hipLaunchKernelGGL(conv_mfma_kernel, dim3(8064), dim3(256), 0, stream,
                       xtb, wt, cbias, gw, sc, m, partials);

    hipLaunchKernelGGL(stats_kernel, dim3(NB * NG), dim3(64), 0, stream,
                       partials, stats);

    int total4 = (NB * COUT * HP * WP) / 4;
    hipLaunchKernelGGL(final_kernel, dim3((total4 + 255) / 256), dim3(256), 0, stream,
                       (const f32x4*)m, stats, gw, gb, sc, (f32x4*)d_out);
}